// Round 1
// baseline (878.518 us; speedup 1.0000x reference)
//
#include <hip/hip_runtime.h>
#include <math.h>

// Problem constants: B=8, C=64, H=W=256, fp32 in/out.
constexpr int CH  = 64;      // channels
constexpr int WW  = 256;     // H == W
constexpr int HWS = WW * WW; // 65536 elements per (b,c) slab
constexpr int NB  = 8;       // batch

typedef __attribute__((ext_vector_type(8))) short bf16x8;
typedef __attribute__((ext_vector_type(4))) float f32x4;

// RNE fp32 -> bf16 (manual; data is finite)
__device__ inline ushort f2bf(float f) {
    uint u = __float_as_uint(f);
    u += 0x7fffu + ((u >> 16) & 1u);
    return (ushort)(u >> 16);
}

// ---------------------------------------------------------------------------
// Kernel 0: weight prep. WtG[c][m] = W_mat[o][c]  (m = mat*64+o, 192 wide),
// BiasG[m]. 48.75 KB total, written into the (currently dead) Vt region.
// Runs every iteration (transpose_v later overwrites the region) - ~3 us.
// ---------------------------------------------------------------------------
__global__ __launch_bounds__(256) void prep_weights(
    const float* __restrict__ Wq, const float* __restrict__ Wk, const float* __restrict__ Wv,
    const float* __restrict__ bq, const float* __restrict__ bk, const float* __restrict__ bv,
    float* __restrict__ WtG, float* __restrict__ BiasG)
{
    const int i = blockIdx.x * 256 + threadIdx.x;
    if (i < 12288) {
        const int c   = i / 192;
        const int m   = i - c * 192;
        const int mat = m >> 6;
        const int o   = m & 63;
        const float* W = (mat == 0) ? Wq : (mat == 1) ? Wk : Wv;
        WtG[i] = W[o * 64 + c];
    } else if (i < 12480) {
        const int m   = i - 12288;
        const int mat = m >> 6;
        const int o   = m & 63;
        const float* bsrc = (mat == 0) ? bq : (mat == 1) ? bk : bv;
        BiasG[m] = bsrc[o];
    }
}

// ---------------------------------------------------------------------------
// Kernel 1: fused QKV projection GEMM.  C[192 x 524288] = W[192x64] * X[64x524288]
// Weights are wave-uniform: each wave owns a 48-channel group, reads weights
// via the SCALAR pipe (s_load) and feeds v_fma_f32 with SGPR operands.
// LDS holds only the 8x128 x-tile (double-buffered, 8 KB) -> occupancy up,
// LDS bandwidth no longer the bottleneck (was 6 b128 weight reads per kk).
// Q,K written fp32; V written bf16 (feeds MFMA PV).
// ---------------------------------------------------------------------------
__global__ __launch_bounds__(256) void qkv_kernel3(
    const float* __restrict__ x,
    const float* __restrict__ WtG, const float* __restrict__ BiasG,
    float* __restrict__ Q, float* __restrict__ K, ushort* __restrict__ V)
{
    __shared__ float Xs[2][8][128];   // double-buffered K-chunk x N-tile (8 KB)

    const int tid = threadIdx.x;
    // wave id, forced wave-uniform so weight indexing scalarizes to s_load
    const int g   = __builtin_amdgcn_readfirstlane(tid >> 6);   // 0..3
    const int ln  = tid & 63;
    const int px  = ln * 2;           // 2 pixels per lane

    const int n0  = blockIdx.x * 128; // global pixel tile
    const int b   = n0 >> 16;
    const int pb  = n0 & 65535;

    const float* xb = x + ((size_t)b << 22);   // b*64*65536

    const int srow = tid >> 5;        // 0..7   (staging row)
    const int scol = (tid & 31) * 4;  // 0..124 (staging col, float4)

    float2 acc[48];
#pragma unroll
    for (int m = 0; m < 48; ++m) acc[m] = make_float2(0.f, 0.f);

    // prologue: stage c0=0 into buf 0
    *(float4*)&Xs[0][srow][scol] =
        *(const float4*)&xb[((size_t)srow << 16) + pb + scol];

    for (int c0 = 0; c0 < CH; c0 += 8) {
        const int buf = (c0 >> 3) & 1;
        __syncthreads();              // staged tile visible; prev reads done
        if (c0 + 8 < CH) {
            *(float4*)&Xs[buf ^ 1][srow][scol] =
                *(const float4*)&xb[((size_t)(c0 + 8 + srow) << 16) + pb + scol];
        }
#pragma unroll
        for (int kk = 0; kk < 8; ++kk) {
            // wave-uniform weight row: 48 floats -> 12 s_load_dwordx4
            const float* wr = WtG + (c0 + kk) * 192 + g * 48;
            float w[48];
#pragma unroll
            for (int q4 = 0; q4 < 12; ++q4)
                *(float4*)&w[q4 * 4] = *(const float4*)&wr[q4 * 4];
            const float2 xv = *(const float2*)&Xs[buf][kk][px];
#pragma unroll
            for (int m = 0; m < 48; ++m) {
                acc[m].x = fmaf(w[m], xv.x, acc[m].x);
                acc[m].y = fmaf(w[m], xv.y, acc[m].y);
            }
        }
    }

#pragma unroll
    for (int m = 0; m < 48; ++m) {
        const int gm  = g * 48 + m;
        const int mat = gm >> 6;      // wave-uniform branch
        const int ch  = gm & 63;
        const float bias = BiasG[gm]; // uniform -> s_load
        float2 r = acc[m];
        r.x += bias; r.y += bias;
        const size_t oidx = ((size_t)(b * CH + ch) << 16) + pb + px;
        if (mat == 0)      *(float2*)&Q[oidx] = r;
        else if (mat == 1) *(float2*)&K[oidx] = r;
        else {
            ushort2 vs;
            vs.x = f2bf(r.x); vs.y = f2bf(r.y);
            *(ushort2*)&V[oidx] = vs;
        }
    }
}

// ---------------------------------------------------------------------------
// Kernel 2: attn[b,c,i,j] = sum_h q[b,c,h,i] * k[b,c,h,j]  (fp32 this round)
// ---------------------------------------------------------------------------
__global__ __launch_bounds__(256) void attn_kernel(
    const float* __restrict__ Q, const float* __restrict__ Kt,
    float* __restrict__ attn)
{
    const int gid = blockIdx.x;
    const int bc  = gid >> 2;
    const int i0  = ((gid >> 1) & 1) * 128;
    const int j0  = (gid & 1) * 128;
    const float* q = Q  + (size_t)bc * HWS;
    const float* k = Kt + (size_t)bc * HWS;
    float* out     = attn + (size_t)bc * HWS;

    __shared__ float As[8][128];
    __shared__ float Bs[8][128];

    const int tid = threadIdx.x;
    const int tx  = tid & 15;
    const int ty  = tid >> 4;

    float acc[8][8];
#pragma unroll
    for (int u = 0; u < 8; ++u)
#pragma unroll
        for (int w = 0; w < 8; ++w) acc[u][w] = 0.f;

    const int sflat = tid * 4;
    const int skk   = sflat >> 7;
    const int sii   = sflat & 127;

    for (int k0 = 0; k0 < WW; k0 += 8) {
        *(float4*)&As[skk][sii] = *(const float4*)&q[(k0 + skk) * WW + i0 + sii];
        *(float4*)&Bs[skk][sii] = *(const float4*)&k[(k0 + skk) * WW + j0 + sii];
        __syncthreads();
#pragma unroll
        for (int kk = 0; kk < 8; ++kk) {
            float a[8], bvv[8];
#pragma unroll
            for (int u = 0; u < 8; ++u) a[u]   = As[kk][ty * 8 + u];
#pragma unroll
            for (int u = 0; u < 8; ++u) bvv[u] = Bs[kk][tx * 8 + u];
#pragma unroll
            for (int u = 0; u < 8; ++u)
#pragma unroll
                for (int w = 0; w < 8; ++w)
                    acc[u][w] = fmaf(a[u], bvv[w], acc[u][w]);
        }
        __syncthreads();
    }
#pragma unroll
    for (int u = 0; u < 8; ++u) {
        float* row = out + (size_t)(i0 + ty * 8 + u) * WW + j0 + tx * 8;
#pragma unroll
        for (int w = 0; w < 8; ++w) row[w] = acc[u][w];
    }
}

// ---------------------------------------------------------------------------
// Kernel 3: transpose V (bf16): Vt[b,c,j,m] = Vb[b,c,m,j].
// 128x128 LDS tile, row-group rotation swizzle, b128 LDS ops, coalesced
// global loads and stores.
// ---------------------------------------------------------------------------
__global__ __launch_bounds__(256) void transpose_v(
    const ushort* __restrict__ Vb, ushort* __restrict__ Vt)
{
    const int blk = blockIdx.x;
    const int bc  = blk >> 2;
    const int m0  = ((blk >> 1) & 1) * 128;
    const int j0  = (blk & 1) * 128;
    const ushort* src = Vb + (size_t)bc * HWS;
    ushort* dst       = Vt + (size_t)bc * HWS;

    __shared__ ushort T[128][128] __attribute__((aligned(16)));

    const int tid = threadIdx.x;
#pragma unroll
    for (int p = 0; p < 8; ++p) {
        const int id  = p * 256 + tid;
        const int mm  = id >> 4;
        const int c16 = id & 15;               // jj-group
        const int cg  = (c16 + (mm >> 3)) & 15;
        *(uint4*)&T[mm][cg * 8] =
            *(const uint4*)(src + (size_t)(m0 + mm) * WW + j0 + c16 * 8);
    }
    __syncthreads();
#pragma unroll
    for (int p = 0; p < 4; ++p) {
        const int id  = p * 256 + tid;
        const int c16 = id & 15;               // m-chunk (lane-fast => coalesced stores)
        const int jjp = id >> 4;               // 0..63 (row pair)
        const int jj  = jjp * 2;
        const int jjg = jj >> 3;
        ushort ra[8], rb[8];
#pragma unroll
        for (int u = 0; u < 8; ++u) {
            const int mm = c16 * 8 + u;        // mm>>3 == c16
            const int cg = (jjg + c16) & 15;
            const uint pr = *(const uint*)&T[mm][cg * 8 + (jj & 7)];
            ra[u] = (ushort)(pr & 0xffffu);
            rb[u] = (ushort)(pr >> 16);
        }
        *(uint4*)(dst + (size_t)(j0 + jj)     * WW + m0 + c16 * 8) = *(uint4*)ra;
        *(uint4*)(dst + (size_t)(j0 + jj + 1) * WW + m0 + c16 * 8) = *(uint4*)rb;
    }
}

// ---------------------------------------------------------------------------
// Kernel 4: channel softmax, fp32 logits in -> bf16 weights out.
// ---------------------------------------------------------------------------
__global__ __launch_bounds__(128) void softmax_kernel(
    const float* __restrict__ logits, ushort* __restrict__ Wb)
{
    const int gid = blockIdx.x;            // b*256 + i
    const int b   = gid >> 8;
    const int i   = gid & 255;
    const int j2  = threadIdx.x * 2;
    const size_t off = (((size_t)(b * CH)) << 16) + (size_t)i * WW + j2;
    const float* base = logits + off;
    ushort* wout      = Wb + off;

    float2 v[CH];
#pragma unroll
    for (int c = 0; c < CH; ++c) v[c] = *(const float2*)&base[((size_t)c) << 16];

    float mx = v[0].x, my = v[0].y;
#pragma unroll
    for (int c = 1; c < CH; ++c) { mx = fmaxf(mx, v[c].x); my = fmaxf(my, v[c].y); }

    float sx = 0.f, sy = 0.f;
#pragma unroll
    for (int c = 0; c < CH; ++c) {
        v[c].x = __expf(v[c].x - mx); sx += v[c].x;
        v[c].y = __expf(v[c].y - my); sy += v[c].y;
    }
    const float ix = 1.0f / sx, iy = 1.0f / sy;
#pragma unroll
    for (int c = 0; c < CH; ++c) {
        ushort2 o;
        o.x = f2bf(v[c].x * ix);
        o.y = f2bf(v[c].y * iy);
        *(ushort2*)&wout[((size_t)c) << 16] = o;
    }
}

// ---------------------------------------------------------------------------
// Kernel 5: PV via bf16 MFMA.  out[i][j] = sum_m w[i][m] * v[m][j], per (b,c).
// A = w [i][m] (k-contiguous), B = Vt [j][m] (k-contiguous). fp32 accumulate.
// 128x128 block tile, 4 waves each 64x64 (4x4 MFMA 16x16x32 tiles).
// ---------------------------------------------------------------------------
__global__ __launch_bounds__(256) void pv_kernel2(
    const ushort* __restrict__ Wb, const ushort* __restrict__ Vt,
    float* __restrict__ out)
{
    const int blk = blockIdx.x;
    const int bc  = blk >> 2;
    const int i0  = ((blk >> 1) & 1) * 128;
    const int j0  = (blk & 1) * 128;
    const ushort* w  = Wb + (size_t)bc * HWS;
    const ushort* vt = Vt + (size_t)bc * HWS;
    float* o         = out + (size_t)bc * HWS;

    __shared__ ushort As[128][40] __attribute__((aligned(16)));
    __shared__ ushort Bs[128][40] __attribute__((aligned(16)));

    const int tid  = threadIdx.x;
    const int L    = tid & 63;
    const int wid  = tid >> 6;
    const int wy   = (wid >> 1) * 64;
    const int wx   = (wid & 1) * 64;
    const int ml   = L & 15;
    const int quad = L >> 4;

    f32x4 zero = {0.f, 0.f, 0.f, 0.f};
    f32x4 acc[4][4];
#pragma unroll
    for (int a = 0; a < 4; ++a)
#pragma unroll
        for (int b = 0; b < 4; ++b) acc[a][b] = zero;

    for (int m0 = 0; m0 < WW; m0 += 32) {
#pragma unroll
        for (int p = 0; p < 2; ++p) {
            const int id  = p * 256 + tid;
            const int row = id >> 2;
            const int c4  = id & 3;
            *(uint4*)&As[row][c4 * 8] =
                *(const uint4*)(w  + (size_t)(i0 + row) * WW + m0 + c4 * 8);
            *(uint4*)&Bs[row][c4 * 8] =
                *(const uint4*)(vt + (size_t)(j0 + row) * WW + m0 + c4 * 8);
        }
        __syncthreads();

        bf16x8 af[4], bfr[4];
#pragma unroll
        for (int t = 0; t < 4; ++t)
            af[t]  = *(const bf16x8*)&As[wy + t * 16 + ml][quad * 8];
#pragma unroll
        for (int t = 0; t < 4; ++t)
            bfr[t] = *(const bf16x8*)&Bs[wx + t * 16 + ml][quad * 8];
#pragma unroll
        for (int a = 0; a < 4; ++a)
#pragma unroll
            for (int b = 0; b < 4; ++b)
                acc[a][b] = __builtin_amdgcn_mfma_f32_16x16x32_bf16(
                    af[a], bfr[b], acc[a][b], 0, 0, 0);
        __syncthreads();
    }

    // C/D layout: col = lane&15, row = quad*4 + reg
#pragma unroll
    for (int a = 0; a < 4; ++a)
#pragma unroll
        for (int b = 0; b < 4; ++b)
#pragma unroll
            for (int r = 0; r < 4; ++r)
                o[(size_t)(i0 + wy + a * 16 + quad * 4 + r) * WW
                  + j0 + wx + b * 16 + ml] = acc[a][b][r];
}

// ---------------------------------------------------------------------------
extern "C" void kernel_launch(void* const* d_in, const int* in_sizes, int n_in,
                              void* d_out, int out_size, void* d_ws, size_t ws_size,
                              hipStream_t stream) {
    const float* x  = (const float*)d_in[0];
    const float* Wq = (const float*)d_in[1];
    const float* bq = (const float*)d_in[2];
    const float* Wk = (const float*)d_in[3];
    const float* bk = (const float*)d_in[4];
    const float* Wv = (const float*)d_in[5];
    const float* bv = (const float*)d_in[6];
    float* out = (float*)d_out;

    // ws layout (402.7 MB):
    //   Q fp32 [134MB] | K fp32 [134MB] | Vb bf16 [67MB] | Vt bf16 [67MB]
    //   Wb (softmax bf16) aliases Q — Q is dead after attn_kernel.
    //   WtG/BiasG (48.75 KB) alias the head of Vt — Vt is written only by
    //   transpose_v, which runs after qkv has consumed the weights; prep
    //   re-runs every iteration so the overwrite is harmless.
    const size_t NEL = (size_t)NB * CH * HWS;       // 33,554,432
    float*  Q  = (float*)d_ws;
    float*  K  = Q + NEL;
    ushort* Vb = (ushort*)(K + NEL);
    ushort* Vt = Vb + NEL;
    ushort* Wb = (ushort*)d_ws;                     // alias Q
    float*  WtG   = (float*)Vt;                     // alias Vt head
    float*  BiasG = WtG + 12288;

    prep_weights<<<49, 256, 0, stream>>>(Wq, Wk, Wv, bq, bk, bv, WtG, BiasG);
    qkv_kernel3<<<(NB * HWS) / 128, 256, 0, stream>>>(x, WtG, BiasG, Q, K, Vb);
    attn_kernel<<<NB * CH * 4, 256, 0, stream>>>(Q, K, out);
    transpose_v<<<NB * CH * 4, 256, 0, stream>>>(Vb, Vt);
    softmax_kernel<<<NB * WW, 128, 0, stream>>>(out, Wb);
    pv_kernel2<<<NB * CH * 4, 256, 0, stream>>>(Wb, Vt, out);
}

// Round 2
// 701.801 us; speedup vs baseline: 1.2518x; 1.2518x over previous
//
#include <hip/hip_runtime.h>
#include <math.h>

// Problem constants: B=8, C=64, H=W=256, fp32 in/out.
constexpr int CH  = 64;      // channels
constexpr int WW  = 256;     // H == W
constexpr int HWS = WW * WW; // 65536 elements per (b,c) slab
constexpr int NB  = 8;       // batch

typedef __attribute__((ext_vector_type(8))) short bf16x8;
typedef __attribute__((ext_vector_type(4))) float f32x4;

// RNE fp32 -> bf16 (manual; data is finite)
__device__ inline ushort f2bf(float f) {
    uint u = __float_as_uint(f);
    u += 0x7fffu + ((u >> 16) & 1u);
    return (ushort)(u >> 16);
}

// ---------------------------------------------------------------------------
// Kernel 1: fused QKV projection GEMM.  C[192 x 524288] = W[192x64] * X[64x524288]
// Q,K written fp32 [h][i]; V written bf16 (feeds MFMA PV).
// (Reverted to the R0 form: LDS-staged weights, broadcast reads. The s_load
//  variant serialized on scalar-cache latency in the inner loop: 373 us.)
// ---------------------------------------------------------------------------
__global__ __launch_bounds__(256) void qkv_kernel2(
    const float* __restrict__ x,
    const float* __restrict__ Wq, const float* __restrict__ bq,
    const float* __restrict__ Wk, const float* __restrict__ bk,
    const float* __restrict__ Wv, const float* __restrict__ bv,
    float* __restrict__ Q, float* __restrict__ K, ushort* __restrict__ V)
{
    __shared__ float Wt[64][192];   // [c][m], m = mat*64 + o   (48 KB)
    __shared__ float Bias[192];
    __shared__ float Xs[8][128];    // K-chunk x N-tile          (4 KB)

    const int tid = threadIdx.x;
    const int n0  = blockIdx.x * 128;   // global pixel
    const int b   = n0 >> 16;
    const int pb  = n0 & 65535;

    // Stage weights transposed. Lane-major over o => consecutive LDS addrs.
    {
        const float* Wsrc[3] = {Wq, Wk, Wv};
#pragma unroll
        for (int mat = 0; mat < 3; ++mat) {
#pragma unroll
            for (int r = 0; r < 4; ++r) {
                const int flat = r * 256 + tid;   // 0..1023
                const int o    = flat & 63;       // consecutive across lanes
                const int c4   = (flat >> 6) * 4; // 0,4,...,60
                const float4 w = *(const float4*)&Wsrc[mat][o * 64 + c4];
                Wt[c4 + 0][mat * 64 + o] = w.x;
                Wt[c4 + 1][mat * 64 + o] = w.y;
                Wt[c4 + 2][mat * 64 + o] = w.z;
                Wt[c4 + 3][mat * 64 + o] = w.w;
            }
        }
        if (tid < 192)
            Bias[tid] = (tid < 64) ? bq[tid] : ((tid < 128) ? bk[tid - 64] : bv[tid - 128]);
    }

    const int mg  = tid >> 5;        // 0..7
    const int ng  = tid & 31;        // 0..31
    const int m0  = mg * 24;
    const int pix = ng * 4;

    float4 acc[24];
#pragma unroll
    for (int m = 0; m < 24; ++m) acc[m] = make_float4(0.f, 0.f, 0.f, 0.f);

    const int skk = tid >> 5;
    const int sp4 = (tid & 31) * 4;

    for (int c0 = 0; c0 < CH; c0 += 8) {
        __syncthreads();
        *(float4*)&Xs[skk][sp4] =
            *(const float4*)&x[((size_t)(b * CH + c0 + skk) << 16) + pb + sp4];
        __syncthreads();

#pragma unroll
        for (int kk = 0; kk < 8; ++kk) {
            float wv[24];
#pragma unroll
            for (int q4 = 0; q4 < 6; ++q4)
                *(float4*)&wv[q4 * 4] = *(const float4*)&Wt[c0 + kk][m0 + q4 * 4];
            const float4 xv = *(const float4*)&Xs[kk][pix];
#pragma unroll
            for (int m = 0; m < 24; ++m) {
                acc[m].x = fmaf(wv[m], xv.x, acc[m].x);
                acc[m].y = fmaf(wv[m], xv.y, acc[m].y);
                acc[m].z = fmaf(wv[m], xv.z, acc[m].z);
                acc[m].w = fmaf(wv[m], xv.w, acc[m].w);
            }
        }
    }

#pragma unroll
    for (int m = 0; m < 24; ++m) {
        const int gm  = m0 + m;
        const int mat = gm >> 6;
        const int ch  = gm & 63;
        const float bias = Bias[gm];
        float4 r = acc[m];
        r.x += bias; r.y += bias; r.z += bias; r.w += bias;
        const size_t oidx = ((size_t)(b * CH + ch) << 16) + pb + pix;
        if (mat == 0)      *(float4*)&Q[oidx] = r;
        else if (mat == 1) *(float4*)&K[oidx] = r;
        else {
            ushort4 vs;
            vs.x = f2bf(r.x); vs.y = f2bf(r.y); vs.z = f2bf(r.z); vs.w = f2bf(r.w);
            *(ushort4*)&V[oidx] = vs;
        }
    }
}

// ---------------------------------------------------------------------------
// Kernel 2 (NEW): attn[b,c,i,j] = sum_h q[b,c,h,i] * k[b,c,h,j] via split-bf16
// MFMA: q = q_hi + q_lo (bf16 each, exact fp32 residual path), 3 MFMAs
// (hh + hl + lh) into one fp32 accumulator.  Error ~2^-16 relative on logits.
// Q,K are [h][i] (k-major) so fragments are column reads: stage fp32 tiles
// [32][128] with XOR swizzle (i ^= ((h>>1)&7)<<2) -> per-quad b32 fragment
// reads are <=2-way on banks.  Tile/fragment/epilogue pattern cloned from the
// verified pv_kernel2.
// ---------------------------------------------------------------------------
union FragU { uint u[4]; bf16x8 v; };

// Build hi/lo bf16 fragments from staged fp32 tile S (logical [32][128],
// physical col = i ^ ((h>>1)&7)<<2).  col = lane's row/col index; quad = k-group.
__device__ inline void frag_split(const float* __restrict__ S, int col, int quad,
                                  bf16x8* hi, bf16x8* lo) {
    FragU H, L;
#pragma unroll
    for (int rp = 0; rp < 4; ++rp) {
        const int h0 = quad * 8 + rp * 2;          // even h; h0 and h0+1 share swizzle
        const int sw = ((h0 >> 1) & 7) << 2;
        const int c  = col ^ sw;
        const float f0 = S[(h0    ) * 128 + c];
        const float f1 = S[(h0 + 1) * 128 + c];
        const uint u0 = __float_as_uint(f0);
        const uint u1 = __float_as_uint(f1);
        // hi = truncate-to-bf16; lo = exact residual, truncated to bf16
        const float g0 = f0 - __uint_as_float(u0 & 0xffff0000u);
        const float g1 = f1 - __uint_as_float(u1 & 0xffff0000u);
        H.u[rp] = __builtin_amdgcn_perm(u1, u0, 0x07060302u);
        L.u[rp] = __builtin_amdgcn_perm(__float_as_uint(g1), __float_as_uint(g0),
                                        0x07060302u);
    }
    *hi = H.v; *lo = L.v;
}

__global__ __launch_bounds__(256, 3) void attn_mfma(
    const float* __restrict__ Q, const float* __restrict__ Kt,
    float* __restrict__ attn)
{
    const int gid = blockIdx.x;
    const int bc  = gid >> 2;
    const int i0  = ((gid >> 1) & 1) * 128;
    const int j0  = (gid & 1) * 128;
    const float* q = Q  + (size_t)bc * HWS;
    const float* k = Kt + (size_t)bc * HWS;
    float* out     = attn + (size_t)bc * HWS;

    __shared__ float As[32 * 128];   // 16 KB, logical [h][i], XOR-swizzled cols
    __shared__ float Bs[32 * 128];   // 16 KB

    const int tid  = threadIdx.x;
    const int L    = tid & 63;
    const int wid  = tid >> 6;
    const int wy   = (wid >> 1) * 64;
    const int wx   = (wid & 1) * 64;
    const int ml   = L & 15;
    const int quad = L >> 4;

    f32x4 zero = {0.f, 0.f, 0.f, 0.f};
    f32x4 acc[4][4];
#pragma unroll
    for (int a = 0; a < 4; ++a)
#pragma unroll
        for (int b = 0; b < 4; ++b) acc[a][b] = zero;

    for (int k0 = 0; k0 < WW; k0 += 32) {
        // stage: 32h x 128i fp32 per tile, coalesced b128, swizzled cols
#pragma unroll
        for (int p = 0; p < 4; ++p) {
            const int flat = p * 256 + tid;        // 0..1023
            const int hh   = flat >> 5;            // 0..31
            const int i4   = (flat & 31) * 4;
            const int sw   = ((hh >> 1) & 7) << 2;
            *(float4*)&As[hh * 128 + (i4 ^ sw)] =
                *(const float4*)&q[(size_t)(k0 + hh) * WW + i0 + i4];
            *(float4*)&Bs[hh * 128 + (i4 ^ sw)] =
                *(const float4*)&k[(size_t)(k0 + hh) * WW + j0 + i4];
        }
        __syncthreads();

        bf16x8 bh[4], bl[4];
#pragma unroll
        for (int t = 0; t < 4; ++t)
            frag_split(Bs, wx + t * 16 + ml, quad, &bh[t], &bl[t]);
#pragma unroll
        for (int a = 0; a < 4; ++a) {
            bf16x8 ah, al;
            frag_split(As, wy + a * 16 + ml, quad, &ah, &al);
#pragma unroll
            for (int b = 0; b < 4; ++b) {
                acc[a][b] = __builtin_amdgcn_mfma_f32_16x16x32_bf16(ah, bh[b], acc[a][b], 0, 0, 0);
                acc[a][b] = __builtin_amdgcn_mfma_f32_16x16x32_bf16(ah, bl[b], acc[a][b], 0, 0, 0);
                acc[a][b] = __builtin_amdgcn_mfma_f32_16x16x32_bf16(al, bh[b], acc[a][b], 0, 0, 0);
            }
        }
        __syncthreads();
    }

    // C/D layout: col = lane&15, row = quad*4 + reg
#pragma unroll
    for (int a = 0; a < 4; ++a)
#pragma unroll
        for (int b = 0; b < 4; ++b)
#pragma unroll
            for (int r = 0; r < 4; ++r)
                out[(size_t)(i0 + wy + a * 16 + quad * 4 + r) * WW
                    + j0 + wx + b * 16 + ml] = acc[a][b][r];
}

// ---------------------------------------------------------------------------
// Kernel 3: transpose V (bf16): Vt[b,c,j,m] = Vb[b,c,m,j].
// ---------------------------------------------------------------------------
__global__ __launch_bounds__(256) void transpose_v(
    const ushort* __restrict__ Vb, ushort* __restrict__ Vt)
{
    const int blk = blockIdx.x;
    const int bc  = blk >> 2;
    const int m0  = ((blk >> 1) & 1) * 128;
    const int j0  = (blk & 1) * 128;
    const ushort* src = Vb + (size_t)bc * HWS;
    ushort* dst       = Vt + (size_t)bc * HWS;

    __shared__ ushort T[128][128] __attribute__((aligned(16)));

    const int tid = threadIdx.x;
#pragma unroll
    for (int p = 0; p < 8; ++p) {
        const int id  = p * 256 + tid;
        const int mm  = id >> 4;
        const int c16 = id & 15;               // jj-group
        const int cg  = (c16 + (mm >> 3)) & 15;
        *(uint4*)&T[mm][cg * 8] =
            *(const uint4*)(src + (size_t)(m0 + mm) * WW + j0 + c16 * 8);
    }
    __syncthreads();
#pragma unroll
    for (int p = 0; p < 4; ++p) {
        const int id  = p * 256 + tid;
        const int c16 = id & 15;               // m-chunk (lane-fast => coalesced stores)
        const int jjp = id >> 4;               // 0..63 (row pair)
        const int jj  = jjp * 2;
        const int jjg = jj >> 3;
        ushort ra[8], rb[8];
#pragma unroll
        for (int u = 0; u < 8; ++u) {
            const int mm = c16 * 8 + u;        // mm>>3 == c16
            const int cg = (jjg + c16) & 15;
            const uint pr = *(const uint*)&T[mm][cg * 8 + (jj & 7)];
            ra[u] = (ushort)(pr & 0xffffu);
            rb[u] = (ushort)(pr >> 16);
        }
        *(uint4*)(dst + (size_t)(j0 + jj)     * WW + m0 + c16 * 8) = *(uint4*)ra;
        *(uint4*)(dst + (size_t)(j0 + jj + 1) * WW + m0 + c16 * 8) = *(uint4*)rb;
    }
}

// ---------------------------------------------------------------------------
// Kernel 4: channel softmax, fp32 logits in -> bf16 weights out.
// ---------------------------------------------------------------------------
__global__ __launch_bounds__(128) void softmax_kernel(
    const float* __restrict__ logits, ushort* __restrict__ Wb)
{
    const int gid = blockIdx.x;            // b*256 + i
    const int b   = gid >> 8;
    const int i   = gid & 255;
    const int j2  = threadIdx.x * 2;
    const size_t off = (((size_t)(b * CH)) << 16) + (size_t)i * WW + j2;
    const float* base = logits + off;
    ushort* wout      = Wb + off;

    float2 v[CH];
#pragma unroll
    for (int c = 0; c < CH; ++c) v[c] = *(const float2*)&base[((size_t)c) << 16];

    float mx = v[0].x, my = v[0].y;
#pragma unroll
    for (int c = 1; c < CH; ++c) { mx = fmaxf(mx, v[c].x); my = fmaxf(my, v[c].y); }

    float sx = 0.f, sy = 0.f;
#pragma unroll
    for (int c = 0; c < CH; ++c) {
        v[c].x = __expf(v[c].x - mx); sx += v[c].x;
        v[c].y = __expf(v[c].y - my); sy += v[c].y;
    }
    const float ix = 1.0f / sx, iy = 1.0f / sy;
#pragma unroll
    for (int c = 0; c < CH; ++c) {
        ushort2 o;
        o.x = f2bf(v[c].x * ix);
        o.y = f2bf(v[c].y * iy);
        *(ushort2*)&wout[((size_t)c) << 16] = o;
    }
}

// ---------------------------------------------------------------------------
// Kernel 5: PV via bf16 MFMA.  out[i][j] = sum_m w[i][m] * v[m][j], per (b,c).
// A = w [i][m] (k-contiguous), B = Vt [j][m] (k-contiguous). fp32 accumulate.
// 128x128 block tile, 4 waves each 64x64 (4x4 MFMA 16x16x32 tiles).
// ---------------------------------------------------------------------------
__global__ __launch_bounds__(256) void pv_kernel2(
    const ushort* __restrict__ Wb, const ushort* __restrict__ Vt,
    float* __restrict__ out)
{
    const int blk = blockIdx.x;
    const int bc  = blk >> 2;
    const int i0  = ((blk >> 1) & 1) * 128;
    const int j0  = (blk & 1) * 128;
    const ushort* w  = Wb + (size_t)bc * HWS;
    const ushort* vt = Vt + (size_t)bc * HWS;
    float* o         = out + (size_t)bc * HWS;

    __shared__ ushort As[128][40] __attribute__((aligned(16)));
    __shared__ ushort Bs[128][40] __attribute__((aligned(16)));

    const int tid  = threadIdx.x;
    const int L    = tid & 63;
    const int wid  = tid >> 6;
    const int wy   = (wid >> 1) * 64;
    const int wx   = (wid & 1) * 64;
    const int ml   = L & 15;
    const int quad = L >> 4;

    f32x4 zero = {0.f, 0.f, 0.f, 0.f};
    f32x4 acc[4][4];
#pragma unroll
    for (int a = 0; a < 4; ++a)
#pragma unroll
        for (int b = 0; b < 4; ++b) acc[a][b] = zero;

    for (int m0 = 0; m0 < WW; m0 += 32) {
#pragma unroll
        for (int p = 0; p < 2; ++p) {
            const int id  = p * 256 + tid;
            const int row = id >> 2;
            const int c4  = id & 3;
            *(uint4*)&As[row][c4 * 8] =
                *(const uint4*)(w  + (size_t)(i0 + row) * WW + m0 + c4 * 8);
            *(uint4*)&Bs[row][c4 * 8] =
                *(const uint4*)(vt + (size_t)(j0 + row) * WW + m0 + c4 * 8);
        }
        __syncthreads();

        bf16x8 af[4], bfr[4];
#pragma unroll
        for (int t = 0; t < 4; ++t)
            af[t]  = *(const bf16x8*)&As[wy + t * 16 + ml][quad * 8];
#pragma unroll
        for (int t = 0; t < 4; ++t)
            bfr[t] = *(const bf16x8*)&Bs[wx + t * 16 + ml][quad * 8];
#pragma unroll
        for (int a = 0; a < 4; ++a)
#pragma unroll
            for (int b = 0; b < 4; ++b)
                acc[a][b] = __builtin_amdgcn_mfma_f32_16x16x32_bf16(
                    af[a], bfr[b], acc[a][b], 0, 0, 0);
        __syncthreads();
    }

    // C/D layout: col = lane&15, row = quad*4 + reg
#pragma unroll
    for (int a = 0; a < 4; ++a)
#pragma unroll
        for (int b = 0; b < 4; ++b)
#pragma unroll
            for (int r = 0; r < 4; ++r)
                o[(size_t)(i0 + wy + a * 16 + quad * 4 + r) * WW
                  + j0 + wx + b * 16 + ml] = acc[a][b][r];
}

// ---------------------------------------------------------------------------
extern "C" void kernel_launch(void* const* d_in, const int* in_sizes, int n_in,
                              void* d_out, int out_size, void* d_ws, size_t ws_size,
                              hipStream_t stream) {
    const float* x  = (const float*)d_in[0];
    const float* Wq = (const float*)d_in[1];
    const float* bq = (const float*)d_in[2];
    const float* Wk = (const float*)d_in[3];
    const float* bk = (const float*)d_in[4];
    const float* Wv = (const float*)d_in[5];
    const float* bv = (const float*)d_in[6];
    float* out = (float*)d_out;

    // ws layout (402.7 MB):
    //   Q fp32 [134MB] | K fp32 [134MB] | Vb bf16 [67MB] | Vt bf16 [67MB]
    //   Wb (softmax bf16) aliases Q — Q is dead after attn_mfma.
    const size_t NEL = (size_t)NB * CH * HWS;       // 33,554,432
    float*  Q  = (float*)d_ws;
    float*  K  = Q + NEL;
    ushort* Vb = (ushort*)(K + NEL);
    ushort* Vt = Vb + NEL;
    ushort* Wb = (ushort*)d_ws;                     // alias Q

    qkv_kernel2<<<(NB * HWS) / 128, 256, 0, stream>>>(x, Wq, bq, Wk, bk, Wv, bv, Q, K, Vb);
    attn_mfma<<<NB * CH * 4, 256, 0, stream>>>(Q, K, out);
    transpose_v<<<NB * CH * 4, 256, 0, stream>>>(Vb, Vt);
    softmax_kernel<<<NB * WW, 128, 0, stream>>>(out, Wb);
    pv_kernel2<<<NB * CH * 4, 256, 0, stream>>>(Wb, Vt, out);
}

// Round 3
// 615.338 us; speedup vs baseline: 1.4277x; 1.1405x over previous
//
#include <hip/hip_runtime.h>
#include <math.h>

// Problem constants: B=8, C=64, H=W=256, fp32 in/out.
constexpr int CH  = 64;      // channels
constexpr int WW  = 256;     // H == W
constexpr int HWS = WW * WW; // 65536 elements per (b,c) slab
constexpr int NB  = 8;       // batch

typedef __attribute__((ext_vector_type(8))) short bf16x8;
typedef __attribute__((ext_vector_type(4))) float f32x4;

// RNE fp32 -> bf16 (manual; data is finite)
__device__ inline ushort f2bf(float f) {
    uint u = __float_as_uint(f);
    u += 0x7fffu + ((u >> 16) & 1u);
    return (ushort)(u >> 16);
}

union FragU { uint u[4]; bf16x8 v; };

// ---------------------------------------------------------------------------
// Kernel 1 (NEW): fused QKV projection via split-bf16 MFMA.
//   C[192 x 524288] = W[192x64] * X[64x524288],  K=64 staged once per block.
// W hi/lo lives in REGISTERS (each wave owns 3 m-tiles of 16 rows; A-frags
// loaded from global once).  X is staged once as two k-contiguous bf16 planes
// Xhi/Xlo[128px][64c] with XOR granule swizzle (g ^= (px>>1)&7) so b128
// fragment reads are minimum-aliasing on banks.  3 MFMAs (hh+hl+lh) per
// k-frag give ~2^-15 relative error — far below the bf16 softmax-weight
// quantization already in the pipeline.
// Replaces the fp32-FMA qkv (245us, VALU-bound, MfmaUtil 0): memory floor
// is 469 MB ~= 74us; MFMA work ~20us.
// ---------------------------------------------------------------------------
__global__ __launch_bounds__(256) void qkv_mfma(
    const float* __restrict__ x,
    const float* __restrict__ Wq, const float* __restrict__ bq,
    const float* __restrict__ Wk, const float* __restrict__ bk,
    const float* __restrict__ Wv, const float* __restrict__ bv,
    float* __restrict__ Q, float* __restrict__ K, ushort* __restrict__ V)
{
    __shared__ ushort Xhi[128 * 64] __attribute__((aligned(16)));
    __shared__ ushort Xlo[128 * 64] __attribute__((aligned(16)));

    const int tid  = threadIdx.x;
    const int ln   = tid & 63;
    const int wid  = tid >> 6;       // 0..3
    const int ml   = ln & 15;
    const int quad = ln >> 4;

    const int n0 = blockIdx.x * 128; // global pixel tile
    const int b  = n0 >> 16;
    const int pb = n0 & 65535;
    const float* xb = x + ((size_t)(b * CH) << 16);

    // ---- A-fragments: W hi/lo into registers (3 m-tiles x 2 k-frags) ----
    // A-frag layout (verified via pv_kernel2): row = ml, k = quad*8 + j.
    bf16x8 Ah[3][2], Al[3][2];
    float biasv[3][4];
#pragma unroll
    for (int a = 0; a < 3; ++a) {
        const int mt = wid * 3 + a;                 // m-tile 0..11
        const float* Wsrc = (mt < 4) ? Wq : (mt < 8) ? Wk : Wv;
        const float* bsrc = (mt < 4) ? bq : (mt < 8) ? bk : bv;
        const int o = (mt & 3) * 16 + ml;           // output row within matrix
#pragma unroll
        for (int kf = 0; kf < 2; ++kf) {
            FragU Hh, Ll;
#pragma unroll
            for (int rp = 0; rp < 4; ++rp) {
                const float f0 = Wsrc[o * 64 + kf * 32 + quad * 8 + rp * 2];
                const float f1 = Wsrc[o * 64 + kf * 32 + quad * 8 + rp * 2 + 1];
                const uint u0 = __float_as_uint(f0);
                const uint u1 = __float_as_uint(f1);
                const float g0 = f0 - __uint_as_float(u0 & 0xffff0000u);
                const float g1 = f1 - __uint_as_float(u1 & 0xffff0000u);
                Hh.u[rp] = __builtin_amdgcn_perm(u1, u0, 0x07060302u);
                Ll.u[rp] = __builtin_amdgcn_perm(__float_as_uint(g1),
                                                 __float_as_uint(g0), 0x07060302u);
            }
            Ah[a][kf] = Hh.v; Al[a][kf] = Ll.v;
        }
#pragma unroll
        for (int r = 0; r < 4; ++r)
            biasv[a][r] = bsrc[(mt & 3) * 16 + quad * 4 + r];
    }

    // ---- Stage X: fp32 [64c][128px] -> bf16 hi/lo planes [px][c] ----------
    // adr(px,c) = px*64 + ((c>>3 ^ (px>>1)&7)<<3) + (c&7)
#pragma unroll
    for (int p = 0; p < 8; ++p) {
        const int flat = p * 256 + tid;      // 0..2047
        const int c    = flat >> 5;          // 0..63
        const int px4  = (flat & 31) * 4;
        const float4 xv = *(const float4*)&xb[((size_t)c << 16) + pb + px4];
#pragma unroll
        for (int u = 0; u < 4; ++u) {
            const int px = px4 + u;
            const float f = (&xv.x)[u];
            const uint fu = __float_as_uint(f);
            const float lo = f - __uint_as_float(fu & 0xffff0000u);
            const int adr = px * 64 + ((((c >> 3) ^ ((px >> 1) & 7))) << 3) + (c & 7);
            Xhi[adr] = (ushort)(fu >> 16);
            Xlo[adr] = (ushort)(__float_as_uint(lo) >> 16);
        }
    }
    __syncthreads();

    // ---- MFMA: 8 n-tiles x 3 m-tiles x 2 k-frags x 3 products -------------
    f32x4 acc[3][8];
    const f32x4 zero = {0.f, 0.f, 0.f, 0.f};
#pragma unroll
    for (int a = 0; a < 3; ++a)
#pragma unroll
        for (int t = 0; t < 8; ++t) acc[a][t] = zero;

#pragma unroll
    for (int t = 0; t < 8; ++t) {
        const int px = t * 16 + ml;
        bf16x8 Bh[2], Bl[2];
#pragma unroll
        for (int kf = 0; kf < 2; ++kf) {
            const int g   = kf * 4 + quad;
            const int adr = px * 64 + ((g ^ ((px >> 1) & 7)) << 3);
            Bh[kf] = *(const bf16x8*)&Xhi[adr];
            Bl[kf] = *(const bf16x8*)&Xlo[adr];
        }
#pragma unroll
        for (int a = 0; a < 3; ++a) {
#pragma unroll
            for (int kf = 0; kf < 2; ++kf) {
                acc[a][t] = __builtin_amdgcn_mfma_f32_16x16x32_bf16(Ah[a][kf], Bh[kf], acc[a][t], 0, 0, 0);
                acc[a][t] = __builtin_amdgcn_mfma_f32_16x16x32_bf16(Ah[a][kf], Bl[kf], acc[a][t], 0, 0, 0);
                acc[a][t] = __builtin_amdgcn_mfma_f32_16x16x32_bf16(Al[a][kf], Bh[kf], acc[a][t], 0, 0, 0);
            }
        }
    }

    // ---- Epilogue: bias + store.  C/D: col = ml (px), row = quad*4 + r ----
#pragma unroll
    for (int a = 0; a < 3; ++a) {
        const int mt = wid * 3 + a;
        const int ch = (mt & 3) * 16 + quad * 4;    // + r
        if (mt < 4) {
#pragma unroll
            for (int t = 0; t < 8; ++t)
#pragma unroll
                for (int r = 0; r < 4; ++r)
                    Q[((size_t)(b * CH + ch + r) << 16) + pb + t * 16 + ml] =
                        acc[a][t][r] + biasv[a][r];
        } else if (mt < 8) {
#pragma unroll
            for (int t = 0; t < 8; ++t)
#pragma unroll
                for (int r = 0; r < 4; ++r)
                    K[((size_t)(b * CH + ch + r) << 16) + pb + t * 16 + ml] =
                        acc[a][t][r] + biasv[a][r];
        } else {
#pragma unroll
            for (int t = 0; t < 8; ++t)
#pragma unroll
                for (int r = 0; r < 4; ++r)
                    V[((size_t)(b * CH + ch + r) << 16) + pb + t * 16 + ml] =
                        f2bf(acc[a][t][r] + biasv[a][r]);
        }
    }
}

// ---------------------------------------------------------------------------
// Kernel 2: attn[b,c,i,j] = sum_h q[b,c,h,i] * k[b,c,h,j] via split-bf16
// MFMA (hh + hl + lh into fp32 acc).  Q,K are [h][i] (k-major) so fragments
// are column reads: staged fp32 [32][128] tiles, XOR swizzle on cols.
// ---------------------------------------------------------------------------
__device__ inline void frag_split(const float* __restrict__ S, int col, int quad,
                                  bf16x8* hi, bf16x8* lo) {
    FragU H, L;
#pragma unroll
    for (int rp = 0; rp < 4; ++rp) {
        const int h0 = quad * 8 + rp * 2;          // even h; h0 and h0+1 share swizzle
        const int sw = ((h0 >> 1) & 7) << 2;
        const int c  = col ^ sw;
        const float f0 = S[(h0    ) * 128 + c];
        const float f1 = S[(h0 + 1) * 128 + c];
        const uint u0 = __float_as_uint(f0);
        const uint u1 = __float_as_uint(f1);
        const float g0 = f0 - __uint_as_float(u0 & 0xffff0000u);
        const float g1 = f1 - __uint_as_float(u1 & 0xffff0000u);
        H.u[rp] = __builtin_amdgcn_perm(u1, u0, 0x07060302u);
        L.u[rp] = __builtin_amdgcn_perm(__float_as_uint(g1), __float_as_uint(g0),
                                        0x07060302u);
    }
    *hi = H.v; *lo = L.v;
}

__global__ __launch_bounds__(256, 3) void attn_mfma(
    const float* __restrict__ Q, const float* __restrict__ Kt,
    float* __restrict__ attn)
{
    const int gid = blockIdx.x;
    const int bc  = gid >> 2;
    const int i0  = ((gid >> 1) & 1) * 128;
    const int j0  = (gid & 1) * 128;
    const float* q = Q  + (size_t)bc * HWS;
    const float* k = Kt + (size_t)bc * HWS;
    float* out     = attn + (size_t)bc * HWS;

    __shared__ float As[32 * 128];   // 16 KB, logical [h][i], XOR-swizzled cols
    __shared__ float Bs[32 * 128];   // 16 KB

    const int tid  = threadIdx.x;
    const int L    = tid & 63;
    const int wid  = tid >> 6;
    const int wy   = (wid >> 1) * 64;
    const int wx   = (wid & 1) * 64;
    const int ml   = L & 15;
    const int quad = L >> 4;

    f32x4 zero = {0.f, 0.f, 0.f, 0.f};
    f32x4 acc[4][4];
#pragma unroll
    for (int a = 0; a < 4; ++a)
#pragma unroll
        for (int b = 0; b < 4; ++b) acc[a][b] = zero;

    for (int k0 = 0; k0 < WW; k0 += 32) {
        // stage: 32h x 128i fp32 per tile, coalesced b128, swizzled cols
#pragma unroll
        for (int p = 0; p < 4; ++p) {
            const int flat = p * 256 + tid;        // 0..1023
            const int hh   = flat >> 5;            // 0..31
            const int i4   = (flat & 31) * 4;
            const int sw   = ((hh >> 1) & 7) << 2;
            *(float4*)&As[hh * 128 + (i4 ^ sw)] =
                *(const float4*)&q[(size_t)(k0 + hh) * WW + i0 + i4];
            *(float4*)&Bs[hh * 128 + (i4 ^ sw)] =
                *(const float4*)&k[(size_t)(k0 + hh) * WW + j0 + i4];
        }
        __syncthreads();

        bf16x8 bh[4], bl[4];
#pragma unroll
        for (int t = 0; t < 4; ++t)
            frag_split(Bs, wx + t * 16 + ml, quad, &bh[t], &bl[t]);
#pragma unroll
        for (int a = 0; a < 4; ++a) {
            bf16x8 ah, al;
            frag_split(As, wy + a * 16 + ml, quad, &ah, &al);
#pragma unroll
            for (int b = 0; b < 4; ++b) {
                acc[a][b] = __builtin_amdgcn_mfma_f32_16x16x32_bf16(ah, bh[b], acc[a][b], 0, 0, 0);
                acc[a][b] = __builtin_amdgcn_mfma_f32_16x16x32_bf16(ah, bl[b], acc[a][b], 0, 0, 0);
                acc[a][b] = __builtin_amdgcn_mfma_f32_16x16x32_bf16(al, bh[b], acc[a][b], 0, 0, 0);
            }
        }
        __syncthreads();
    }

    // C/D layout: col = lane&15, row = quad*4 + reg
#pragma unroll
    for (int a = 0; a < 4; ++a)
#pragma unroll
        for (int b = 0; b < 4; ++b)
#pragma unroll
            for (int r = 0; r < 4; ++r)
                out[(size_t)(i0 + wy + a * 16 + quad * 4 + r) * WW
                    + j0 + wx + b * 16 + ml] = acc[a][b][r];
}

// ---------------------------------------------------------------------------
// Kernel 3: transpose V (bf16): Vt[b,c,j,m] = Vb[b,c,m,j].
// ---------------------------------------------------------------------------
__global__ __launch_bounds__(256) void transpose_v(
    const ushort* __restrict__ Vb, ushort* __restrict__ Vt)
{
    const int blk = blockIdx.x;
    const int bc  = blk >> 2;
    const int m0  = ((blk >> 1) & 1) * 128;
    const int j0  = (blk & 1) * 128;
    const ushort* src = Vb + (size_t)bc * HWS;
    ushort* dst       = Vt + (size_t)bc * HWS;

    __shared__ ushort T[128][128] __attribute__((aligned(16)));

    const int tid = threadIdx.x;
#pragma unroll
    for (int p = 0; p < 8; ++p) {
        const int id  = p * 256 + tid;
        const int mm  = id >> 4;
        const int c16 = id & 15;               // jj-group
        const int cg  = (c16 + (mm >> 3)) & 15;
        *(uint4*)&T[mm][cg * 8] =
            *(const uint4*)(src + (size_t)(m0 + mm) * WW + j0 + c16 * 8);
    }
    __syncthreads();
#pragma unroll
    for (int p = 0; p < 4; ++p) {
        const int id  = p * 256 + tid;
        const int c16 = id & 15;               // m-chunk (lane-fast => coalesced stores)
        const int jjp = id >> 4;               // 0..63 (row pair)
        const int jj  = jjp * 2;
        const int jjg = jj >> 3;
        ushort ra[8], rb[8];
#pragma unroll
        for (int u = 0; u < 8; ++u) {
            const int mm = c16 * 8 + u;        // mm>>3 == c16
            const int cg = (jjg + c16) & 15;
            const uint pr = *(const uint*)&T[mm][cg * 8 + (jj & 7)];
            ra[u] = (ushort)(pr & 0xffffu);
            rb[u] = (ushort)(pr >> 16);
        }
        *(uint4*)(dst + (size_t)(j0 + jj)     * WW + m0 + c16 * 8) = *(uint4*)ra;
        *(uint4*)(dst + (size_t)(j0 + jj + 1) * WW + m0 + c16 * 8) = *(uint4*)rb;
    }
}

// ---------------------------------------------------------------------------
// Kernel 4: channel softmax, fp32 logits in -> bf16 weights out.
// ---------------------------------------------------------------------------
__global__ __launch_bounds__(128) void softmax_kernel(
    const float* __restrict__ logits, ushort* __restrict__ Wb)
{
    const int gid = blockIdx.x;            // b*256 + i
    const int b   = gid >> 8;
    const int i   = gid & 255;
    const int j2  = threadIdx.x * 2;
    const size_t off = (((size_t)(b * CH)) << 16) + (size_t)i * WW + j2;
    const float* base = logits + off;
    ushort* wout      = Wb + off;

    float2 v[CH];
#pragma unroll
    for (int c = 0; c < CH; ++c) v[c] = *(const float2*)&base[((size_t)c) << 16];

    float mx = v[0].x, my = v[0].y;
#pragma unroll
    for (int c = 1; c < CH; ++c) { mx = fmaxf(mx, v[c].x); my = fmaxf(my, v[c].y); }

    float sx = 0.f, sy = 0.f;
#pragma unroll
    for (int c = 0; c < CH; ++c) {
        v[c].x = __expf(v[c].x - mx); sx += v[c].x;
        v[c].y = __expf(v[c].y - my); sy += v[c].y;
    }
    const float ix = 1.0f / sx, iy = 1.0f / sy;
#pragma unroll
    for (int c = 0; c < CH; ++c) {
        ushort2 o;
        o.x = f2bf(v[c].x * ix);
        o.y = f2bf(v[c].y * iy);
        *(ushort2*)&wout[((size_t)c) << 16] = o;
    }
}

// ---------------------------------------------------------------------------
// Kernel 5: PV via bf16 MFMA.  out[i][j] = sum_m w[i][m] * v[m][j], per (b,c).
// ---------------------------------------------------------------------------
__global__ __launch_bounds__(256) void pv_kernel2(
    const ushort* __restrict__ Wb, const ushort* __restrict__ Vt,
    float* __restrict__ out)
{
    const int blk = blockIdx.x;
    const int bc  = blk >> 2;
    const int i0  = ((blk >> 1) & 1) * 128;
    const int j0  = (blk & 1) * 128;
    const ushort* w  = Wb + (size_t)bc * HWS;
    const ushort* vt = Vt + (size_t)bc * HWS;
    float* o         = out + (size_t)bc * HWS;

    __shared__ ushort As[128][40] __attribute__((aligned(16)));
    __shared__ ushort Bs[128][40] __attribute__((aligned(16)));

    const int tid  = threadIdx.x;
    const int L    = tid & 63;
    const int wid  = tid >> 6;
    const int wy   = (wid >> 1) * 64;
    const int wx   = (wid & 1) * 64;
    const int ml   = L & 15;
    const int quad = L >> 4;

    f32x4 zero = {0.f, 0.f, 0.f, 0.f};
    f32x4 acc[4][4];
#pragma unroll
    for (int a = 0; a < 4; ++a)
#pragma unroll
        for (int b = 0; b < 4; ++b) acc[a][b] = zero;

    for (int m0 = 0; m0 < WW; m0 += 32) {
#pragma unroll
        for (int p = 0; p < 2; ++p) {
            const int id  = p * 256 + tid;
            const int row = id >> 2;
            const int c4  = id & 3;
            *(uint4*)&As[row][c4 * 8] =
                *(const uint4*)(w  + (size_t)(i0 + row) * WW + m0 + c4 * 8);
            *(uint4*)&Bs[row][c4 * 8] =
                *(const uint4*)(vt + (size_t)(j0 + row) * WW + m0 + c4 * 8);
        }
        __syncthreads();

        bf16x8 af[4], bfr[4];
#pragma unroll
        for (int t = 0; t < 4; ++t)
            af[t]  = *(const bf16x8*)&As[wy + t * 16 + ml][quad * 8];
#pragma unroll
        for (int t = 0; t < 4; ++t)
            bfr[t] = *(const bf16x8*)&Bs[wx + t * 16 + ml][quad * 8];
#pragma unroll
        for (int a = 0; a < 4; ++a)
#pragma unroll
            for (int b = 0; b < 4; ++b)
                acc[a][b] = __builtin_amdgcn_mfma_f32_16x16x32_bf16(
                    af[a], bfr[b], acc[a][b], 0, 0, 0);
        __syncthreads();
    }

    // C/D layout: col = lane&15, row = quad*4 + reg
#pragma unroll
    for (int a = 0; a < 4; ++a)
#pragma unroll
        for (int b = 0; b < 4; ++b)
#pragma unroll
            for (int r = 0; r < 4; ++r)
                o[(size_t)(i0 + wy + a * 16 + quad * 4 + r) * WW
                  + j0 + wx + b * 16 + ml] = acc[a][b][r];
}

// ---------------------------------------------------------------------------
extern "C" void kernel_launch(void* const* d_in, const int* in_sizes, int n_in,
                              void* d_out, int out_size, void* d_ws, size_t ws_size,
                              hipStream_t stream) {
    const float* x  = (const float*)d_in[0];
    const float* Wq = (const float*)d_in[1];
    const float* bq = (const float*)d_in[2];
    const float* Wk = (const float*)d_in[3];
    const float* bk = (const float*)d_in[4];
    const float* Wv = (const float*)d_in[5];
    const float* bv = (const float*)d_in[6];
    float* out = (float*)d_out;

    // ws layout (402.7 MB):
    //   Q fp32 [134MB] | K fp32 [134MB] | Vb bf16 [67MB] | Vt bf16 [67MB]
    //   Wb (softmax bf16) aliases Q — Q is dead after attn_mfma.
    const size_t NEL = (size_t)NB * CH * HWS;       // 33,554,432
    float*  Q  = (float*)d_ws;
    float*  K  = Q + NEL;
    ushort* Vb = (ushort*)(K + NEL);
    ushort* Vt = Vb + NEL;
    ushort* Wb = (ushort*)d_ws;                     // alias Q

    qkv_mfma<<<(NB * HWS) / 128, 256, 0, stream>>>(x, Wq, bq, Wk, bk, Wv, bv, Q, K, Vb);
    attn_mfma<<<NB * CH * 4, 256, 0, stream>>>(Q, K, out);
    transpose_v<<<NB * CH * 4, 256, 0, stream>>>(Vb, Vt);
    softmax_kernel<<<NB * WW, 128, 0, stream>>>(out, Wb);
    pv_kernel2<<<NB * CH * 4, 256, 0, stream>>>(Wb, Vt, out);
}

// Round 4
// 566.354 us; speedup vs baseline: 1.5512x; 1.0865x over previous
//
#include <hip/hip_runtime.h>
#include <math.h>

// Problem constants: B=8, C=64, H=W=256, fp32 in/out.
constexpr int CH  = 64;      // channels
constexpr int WW  = 256;     // H == W
constexpr int HWS = WW * WW; // 65536 elements per (b,c) slab
constexpr int NB  = 8;       // batch

typedef __attribute__((ext_vector_type(8))) short bf16x8;
typedef __attribute__((ext_vector_type(4))) float f32x4;

// RNE fp32 -> bf16 (manual; data is finite)
__device__ inline ushort f2bf(float f) {
    uint u = __float_as_uint(f);
    u += 0x7fffu + ((u >> 16) & 1u);
    return (ushort)(u >> 16);
}

// Pack fp32 -> (bf16_hi << 16) | bf16_lo, hi = truncation, lo = trunc(f - hi).
// Bit-identical to the R2/R3 consumer-side frag_split decomposition.
__device__ inline uint packsplit(float f) {
    const uint fu = __float_as_uint(f);
    const float lo = f - __uint_as_float(fu & 0xffff0000u);
    return (fu & 0xffff0000u) | (__float_as_uint(lo) >> 16);
}

union FragU { uint u[4]; bf16x8 v; };

// ---------------------------------------------------------------------------
// Kernel 1: fused QKV projection via split-bf16 MFMA.
//   C[192 x 524288] = W[192x64] * X[64x524288],  K=64 staged once per block.
// Q,K now written as PACKED SPLIT uint (hi|lo bf16) — producer-side split so
// the attn consumer does 8 v_perm per fragment instead of 24 VALU + fp32 LDS.
// V written bf16 (feeds MFMA PV).
// ---------------------------------------------------------------------------
__global__ __launch_bounds__(256) void qkv_mfma(
    const float* __restrict__ x,
    const float* __restrict__ Wq, const float* __restrict__ bq,
    const float* __restrict__ Wk, const float* __restrict__ bk,
    const float* __restrict__ Wv, const float* __restrict__ bv,
    uint* __restrict__ Q, uint* __restrict__ K, ushort* __restrict__ V)
{
    __shared__ ushort Xhi[128 * 64] __attribute__((aligned(16)));
    __shared__ ushort Xlo[128 * 64] __attribute__((aligned(16)));

    const int tid  = threadIdx.x;
    const int ln   = tid & 63;
    const int wid  = tid >> 6;       // 0..3
    const int ml   = ln & 15;
    const int quad = ln >> 4;

    const int n0 = blockIdx.x * 128; // global pixel tile
    const int b  = n0 >> 16;
    const int pb = n0 & 65535;
    const float* xb = x + ((size_t)(b * CH) << 16);

    // ---- A-fragments: W hi/lo into registers (3 m-tiles x 2 k-frags) ----
    bf16x8 Ah[3][2], Al[3][2];
    float biasv[3][4];
#pragma unroll
    for (int a = 0; a < 3; ++a) {
        const int mt = wid * 3 + a;                 // m-tile 0..11
        const float* Wsrc = (mt < 4) ? Wq : (mt < 8) ? Wk : Wv;
        const float* bsrc = (mt < 4) ? bq : (mt < 8) ? bk : bv;
        const int o = (mt & 3) * 16 + ml;           // output row within matrix
#pragma unroll
        for (int kf = 0; kf < 2; ++kf) {
            FragU Hh, Ll;
#pragma unroll
            for (int rp = 0; rp < 4; ++rp) {
                const float f0 = Wsrc[o * 64 + kf * 32 + quad * 8 + rp * 2];
                const float f1 = Wsrc[o * 64 + kf * 32 + quad * 8 + rp * 2 + 1];
                const uint u0 = __float_as_uint(f0);
                const uint u1 = __float_as_uint(f1);
                const float g0 = f0 - __uint_as_float(u0 & 0xffff0000u);
                const float g1 = f1 - __uint_as_float(u1 & 0xffff0000u);
                Hh.u[rp] = __builtin_amdgcn_perm(u1, u0, 0x07060302u);
                Ll.u[rp] = __builtin_amdgcn_perm(__float_as_uint(g1),
                                                 __float_as_uint(g0), 0x07060302u);
            }
            Ah[a][kf] = Hh.v; Al[a][kf] = Ll.v;
        }
#pragma unroll
        for (int r = 0; r < 4; ++r)
            biasv[a][r] = bsrc[(mt & 3) * 16 + quad * 4 + r];
    }

    // ---- Stage X: fp32 [64c][128px] -> bf16 hi/lo planes [px][c] ----------
#pragma unroll
    for (int p = 0; p < 8; ++p) {
        const int flat = p * 256 + tid;      // 0..2047
        const int c    = flat >> 5;          // 0..63
        const int px4  = (flat & 31) * 4;
        const float4 xv = *(const float4*)&xb[((size_t)c << 16) + pb + px4];
#pragma unroll
        for (int u = 0; u < 4; ++u) {
            const int px = px4 + u;
            const float f = (&xv.x)[u];
            const uint fu = __float_as_uint(f);
            const float lo = f - __uint_as_float(fu & 0xffff0000u);
            const int adr = px * 64 + ((((c >> 3) ^ ((px >> 1) & 7))) << 3) + (c & 7);
            Xhi[adr] = (ushort)(fu >> 16);
            Xlo[adr] = (ushort)(__float_as_uint(lo) >> 16);
        }
    }
    __syncthreads();

    // ---- MFMA: 8 n-tiles x 3 m-tiles x 2 k-frags x 3 products -------------
    f32x4 acc[3][8];
    const f32x4 zero = {0.f, 0.f, 0.f, 0.f};
#pragma unroll
    for (int a = 0; a < 3; ++a)
#pragma unroll
        for (int t = 0; t < 8; ++t) acc[a][t] = zero;

#pragma unroll
    for (int t = 0; t < 8; ++t) {
        const int px = t * 16 + ml;
        bf16x8 Bh[2], Bl[2];
#pragma unroll
        for (int kf = 0; kf < 2; ++kf) {
            const int g   = kf * 4 + quad;
            const int adr = px * 64 + ((g ^ ((px >> 1) & 7)) << 3);
            Bh[kf] = *(const bf16x8*)&Xhi[adr];
            Bl[kf] = *(const bf16x8*)&Xlo[adr];
        }
#pragma unroll
        for (int a = 0; a < 3; ++a) {
#pragma unroll
            for (int kf = 0; kf < 2; ++kf) {
                acc[a][t] = __builtin_amdgcn_mfma_f32_16x16x32_bf16(Ah[a][kf], Bh[kf], acc[a][t], 0, 0, 0);
                acc[a][t] = __builtin_amdgcn_mfma_f32_16x16x32_bf16(Ah[a][kf], Bl[kf], acc[a][t], 0, 0, 0);
                acc[a][t] = __builtin_amdgcn_mfma_f32_16x16x32_bf16(Al[a][kf], Bh[kf], acc[a][t], 0, 0, 0);
            }
        }
    }

    // ---- Epilogue: bias + store.  C/D: col = ml (px), row = quad*4 + r ----
#pragma unroll
    for (int a = 0; a < 3; ++a) {
        const int mt = wid * 3 + a;
        const int ch = (mt & 3) * 16 + quad * 4;    // + r
        if (mt < 4) {
#pragma unroll
            for (int t = 0; t < 8; ++t)
#pragma unroll
                for (int r = 0; r < 4; ++r)
                    Q[((size_t)(b * CH + ch + r) << 16) + pb + t * 16 + ml] =
                        packsplit(acc[a][t][r] + biasv[a][r]);
        } else if (mt < 8) {
#pragma unroll
            for (int t = 0; t < 8; ++t)
#pragma unroll
                for (int r = 0; r < 4; ++r)
                    K[((size_t)(b * CH + ch + r) << 16) + pb + t * 16 + ml] =
                        packsplit(acc[a][t][r] + biasv[a][r]);
        } else {
#pragma unroll
            for (int t = 0; t < 8; ++t)
#pragma unroll
                for (int r = 0; r < 4; ++r)
                    V[((size_t)(b * CH + ch + r) << 16) + pb + t * 16 + ml] =
                        f2bf(acc[a][t][r] + biasv[a][r]);
        }
    }
}

// ---------------------------------------------------------------------------
// Kernel 2 (NEW): attn via split-bf16 MFMA, LDS-FREE.
// Fragments loaded DIRECTLY from global packed-split Q/K (uint hi|lo per
// element).  A fragment = 8 b32 loads at fixed i over 8 h (4x 64B segments
// per instruction across the wave) + 8 v_perm.  No staging, no barriers:
// waves free-run, latency hidden by TLP/MLP; L2 serves the column re-reads
// (~1 GB aggregate at 34.5 TB/s).  Replaces the 64 ds_read_b32 + 192 VALU
// per-chunk consumer-split version (182 us, MfmaUtil 11, all pipes idle).
// ---------------------------------------------------------------------------
__global__ __launch_bounds__(256) void attn_mfma2(
    const uint* __restrict__ Qp, const uint* __restrict__ Kp,
    float* __restrict__ attn)
{
    const int gid = blockIdx.x;
    const int bc  = gid >> 2;
    const int i0  = ((gid >> 1) & 1) * 128;
    const int j0  = (gid & 1) * 128;
    const uint* q = Qp + (size_t)bc * HWS;
    const uint* k = Kp + (size_t)bc * HWS;
    float* out    = attn + (size_t)bc * HWS;

    const int tid  = threadIdx.x;
    const int L    = tid & 63;
    const int wid  = tid >> 6;
    const int wy   = (wid >> 1) * 64;
    const int wx   = (wid & 1) * 64;
    const int ml   = L & 15;
    const int quad = L >> 4;

    const f32x4 zero = {0.f, 0.f, 0.f, 0.f};
    f32x4 acc[4][4];
#pragma unroll
    for (int a = 0; a < 4; ++a)
#pragma unroll
        for (int b = 0; b < 4; ++b) acc[a][b] = zero;

    // per-lane base pointers: column (i0+wy+a*16+ml) / (j0+wx+b*16+ml),
    // row k0 + quad*8 (+j)
    for (int k0 = 0; k0 < WW; k0 += 32) {
        const size_t rb = (size_t)(k0 + quad * 8) * WW;
        uint ua[4][8], ub[4][8];
#pragma unroll
        for (int a = 0; a < 4; ++a) {
            const uint* p = q + rb + i0 + wy + a * 16 + ml;
#pragma unroll
            for (int j = 0; j < 8; ++j) ua[a][j] = p[j * WW];
        }
#pragma unroll
        for (int b = 0; b < 4; ++b) {
            const uint* p = k + rb + j0 + wx + b * 16 + ml;
#pragma unroll
            for (int j = 0; j < 8; ++j) ub[b][j] = p[j * WW];
        }

        bf16x8 Ahf[4], Alf[4], Bhf[4], Blf[4];
#pragma unroll
        for (int a = 0; a < 4; ++a) {
            FragU H, Lo;
#pragma unroll
            for (int rp = 0; rp < 4; ++rp) {
                H.u[rp]  = __builtin_amdgcn_perm(ua[a][rp * 2 + 1], ua[a][rp * 2], 0x07060302u);
                Lo.u[rp] = __builtin_amdgcn_perm(ua[a][rp * 2 + 1], ua[a][rp * 2], 0x05040100u);
            }
            Ahf[a] = H.v; Alf[a] = Lo.v;
        }
#pragma unroll
        for (int b = 0; b < 4; ++b) {
            FragU H, Lo;
#pragma unroll
            for (int rp = 0; rp < 4; ++rp) {
                H.u[rp]  = __builtin_amdgcn_perm(ub[b][rp * 2 + 1], ub[b][rp * 2], 0x07060302u);
                Lo.u[rp] = __builtin_amdgcn_perm(ub[b][rp * 2 + 1], ub[b][rp * 2], 0x05040100u);
            }
            Bhf[b] = H.v; Blf[b] = Lo.v;
        }

#pragma unroll
        for (int a = 0; a < 4; ++a)
#pragma unroll
            for (int b = 0; b < 4; ++b) {
                acc[a][b] = __builtin_amdgcn_mfma_f32_16x16x32_bf16(Ahf[a], Bhf[b], acc[a][b], 0, 0, 0);
                acc[a][b] = __builtin_amdgcn_mfma_f32_16x16x32_bf16(Ahf[a], Blf[b], acc[a][b], 0, 0, 0);
                acc[a][b] = __builtin_amdgcn_mfma_f32_16x16x32_bf16(Alf[a], Bhf[b], acc[a][b], 0, 0, 0);
            }
    }

    // C/D layout: col = lane&15, row = quad*4 + reg
#pragma unroll
    for (int a = 0; a < 4; ++a)
#pragma unroll
        for (int b = 0; b < 4; ++b)
#pragma unroll
            for (int r = 0; r < 4; ++r)
                out[(size_t)(i0 + wy + a * 16 + quad * 4 + r) * WW
                    + j0 + wx + b * 16 + ml] = acc[a][b][r];
}

// ---------------------------------------------------------------------------
// Kernel 3: transpose V (bf16): Vt[b,c,j,m] = Vb[b,c,m,j].
// ---------------------------------------------------------------------------
__global__ __launch_bounds__(256) void transpose_v(
    const ushort* __restrict__ Vb, ushort* __restrict__ Vt)
{
    const int blk = blockIdx.x;
    const int bc  = blk >> 2;
    const int m0  = ((blk >> 1) & 1) * 128;
    const int j0  = (blk & 1) * 128;
    const ushort* src = Vb + (size_t)bc * HWS;
    ushort* dst       = Vt + (size_t)bc * HWS;

    __shared__ ushort T[128][128] __attribute__((aligned(16)));

    const int tid = threadIdx.x;
#pragma unroll
    for (int p = 0; p < 8; ++p) {
        const int id  = p * 256 + tid;
        const int mm  = id >> 4;
        const int c16 = id & 15;               // jj-group
        const int cg  = (c16 + (mm >> 3)) & 15;
        *(uint4*)&T[mm][cg * 8] =
            *(const uint4*)(src + (size_t)(m0 + mm) * WW + j0 + c16 * 8);
    }
    __syncthreads();
#pragma unroll
    for (int p = 0; p < 4; ++p) {
        const int id  = p * 256 + tid;
        const int c16 = id & 15;               // m-chunk (lane-fast => coalesced stores)
        const int jjp = id >> 4;               // 0..63 (row pair)
        const int jj  = jjp * 2;
        const int jjg = jj >> 3;
        ushort ra[8], rb[8];
#pragma unroll
        for (int u = 0; u < 8; ++u) {
            const int mm = c16 * 8 + u;        // mm>>3 == c16
            const int cg = (jjg + c16) & 15;
            const uint pr = *(const uint*)&T[mm][cg * 8 + (jj & 7)];
            ra[u] = (ushort)(pr & 0xffffu);
            rb[u] = (ushort)(pr >> 16);
        }
        *(uint4*)(dst + (size_t)(j0 + jj)     * WW + m0 + c16 * 8) = *(uint4*)ra;
        *(uint4*)(dst + (size_t)(j0 + jj + 1) * WW + m0 + c16 * 8) = *(uint4*)rb;
    }
}

// ---------------------------------------------------------------------------
// Kernel 4: channel softmax, fp32 logits in -> bf16 weights out.
// ---------------------------------------------------------------------------
__global__ __launch_bounds__(128) void softmax_kernel(
    const float* __restrict__ logits, ushort* __restrict__ Wb)
{
    const int gid = blockIdx.x;            // b*256 + i
    const int b   = gid >> 8;
    const int i   = gid & 255;
    const int j2  = threadIdx.x * 2;
    const size_t off = (((size_t)(b * CH)) << 16) + (size_t)i * WW + j2;
    const float* base = logits + off;
    ushort* wout      = Wb + off;

    float2 v[CH];
#pragma unroll
    for (int c = 0; c < CH; ++c) v[c] = *(const float2*)&base[((size_t)c) << 16];

    float mx = v[0].x, my = v[0].y;
#pragma unroll
    for (int c = 1; c < CH; ++c) { mx = fmaxf(mx, v[c].x); my = fmaxf(my, v[c].y); }

    float sx = 0.f, sy = 0.f;
#pragma unroll
    for (int c = 0; c < CH; ++c) {
        v[c].x = __expf(v[c].x - mx); sx += v[c].x;
        v[c].y = __expf(v[c].y - my); sy += v[c].y;
    }
    const float ix = 1.0f / sx, iy = 1.0f / sy;
#pragma unroll
    for (int c = 0; c < CH; ++c) {
        ushort2 o;
        o.x = f2bf(v[c].x * ix);
        o.y = f2bf(v[c].y * iy);
        *(ushort2*)&wout[((size_t)c) << 16] = o;
    }
}

// ---------------------------------------------------------------------------
// Kernel 5: PV via bf16 MFMA.  out[i][j] = sum_m w[i][m] * v[m][j], per (b,c).
// ---------------------------------------------------------------------------
__global__ __launch_bounds__(256) void pv_kernel2(
    const ushort* __restrict__ Wb, const ushort* __restrict__ Vt,
    float* __restrict__ out)
{
    const int blk = blockIdx.x;
    const int bc  = blk >> 2;
    const int i0  = ((blk >> 1) & 1) * 128;
    const int j0  = (blk & 1) * 128;
    const ushort* w  = Wb + (size_t)bc * HWS;
    const ushort* vt = Vt + (size_t)bc * HWS;
    float* o         = out + (size_t)bc * HWS;

    __shared__ ushort As[128][40] __attribute__((aligned(16)));
    __shared__ ushort Bs[128][40] __attribute__((aligned(16)));

    const int tid  = threadIdx.x;
    const int L    = tid & 63;
    const int wid  = tid >> 6;
    const int wy   = (wid >> 1) * 64;
    const int wx   = (wid & 1) * 64;
    const int ml   = L & 15;
    const int quad = L >> 4;

    f32x4 zero = {0.f, 0.f, 0.f, 0.f};
    f32x4 acc[4][4];
#pragma unroll
    for (int a = 0; a < 4; ++a)
#pragma unroll
        for (int b = 0; b < 4; ++b) acc[a][b] = zero;

    for (int m0 = 0; m0 < WW; m0 += 32) {
#pragma unroll
        for (int p = 0; p < 2; ++p) {
            const int id  = p * 256 + tid;
            const int row = id >> 2;
            const int c4  = id & 3;
            *(uint4*)&As[row][c4 * 8] =
                *(const uint4*)(w  + (size_t)(i0 + row) * WW + m0 + c4 * 8);
            *(uint4*)&Bs[row][c4 * 8] =
                *(const uint4*)(vt + (size_t)(j0 + row) * WW + m0 + c4 * 8);
        }
        __syncthreads();

        bf16x8 af[4], bfr[4];
#pragma unroll
        for (int t = 0; t < 4; ++t)
            af[t]  = *(const bf16x8*)&As[wy + t * 16 + ml][quad * 8];
#pragma unroll
        for (int t = 0; t < 4; ++t)
            bfr[t] = *(const bf16x8*)&Bs[wx + t * 16 + ml][quad * 8];
#pragma unroll
        for (int a = 0; a < 4; ++a)
#pragma unroll
            for (int b = 0; b < 4; ++b)
                acc[a][b] = __builtin_amdgcn_mfma_f32_16x16x32_bf16(
                    af[a], bfr[b], acc[a][b], 0, 0, 0);
        __syncthreads();
    }

    // C/D layout: col = lane&15, row = quad*4 + reg
#pragma unroll
    for (int a = 0; a < 4; ++a)
#pragma unroll
        for (int b = 0; b < 4; ++b)
#pragma unroll
            for (int r = 0; r < 4; ++r)
                o[(size_t)(i0 + wy + a * 16 + quad * 4 + r) * WW
                  + j0 + wx + b * 16 + ml] = acc[a][b][r];
}

// ---------------------------------------------------------------------------
extern "C" void kernel_launch(void* const* d_in, const int* in_sizes, int n_in,
                              void* d_out, int out_size, void* d_ws, size_t ws_size,
                              hipStream_t stream) {
    const float* x  = (const float*)d_in[0];
    const float* Wq = (const float*)d_in[1];
    const float* bq = (const float*)d_in[2];
    const float* Wk = (const float*)d_in[3];
    const float* bk = (const float*)d_in[4];
    const float* Wv = (const float*)d_in[5];
    const float* bv = (const float*)d_in[6];
    float* out = (float*)d_out;

    // ws layout (402.7 MB):
    //   Qp uint [134MB] | Kp uint [134MB] | Vb bf16 [67MB] | Vt bf16 [67MB]
    //   Wb (softmax bf16) aliases Qp — Qp is dead after attn_mfma2.
    const size_t NEL = (size_t)NB * CH * HWS;       // 33,554,432
    uint*   Qp = (uint*)d_ws;
    uint*   Kp = Qp + NEL;
    ushort* Vb = (ushort*)(Kp + NEL);
    ushort* Vt = Vb + NEL;
    ushort* Wb = (ushort*)d_ws;                     // alias Qp

    qkv_mfma<<<(NB * HWS) / 128, 256, 0, stream>>>(x, Wq, bq, Wk, bk, Wv, bv, Qp, Kp, Vb);
    attn_mfma2<<<NB * CH * 4, 256, 0, stream>>>(Qp, Kp, out);
    transpose_v<<<NB * CH * 4, 256, 0, stream>>>(Vb, Vt);
    softmax_kernel<<<NB * WW, 128, 0, stream>>>(out, Wb);
    pv_kernel2<<<NB * CH * 4, 256, 0, stream>>>(Wb, Vt, out);
}